// Round 1
// baseline (1337.641 us; speedup 1.0000x reference)
//
#include <hip/hip_runtime.h>
#include <cstdint>
#include <cstddef>

// ---------------------------------------------------------------------------
// Types / helpers
// ---------------------------------------------------------------------------
typedef unsigned short u16;
typedef __attribute__((ext_vector_type(8))) short bf16x8;   // 8 bf16 (4 VGPRs) MFMA operand
typedef __attribute__((ext_vector_type(8))) u16  u16x8;
typedef __attribute__((ext_vector_type(4))) u16  u16x4;
typedef __attribute__((ext_vector_type(4))) float f32x4;    // MFMA accumulator

static __device__ __forceinline__ u16 f2bf(float f) {  // RNE
  unsigned u = __builtin_bit_cast(unsigned, f);
  u += 0x7fffu + ((u >> 16) & 1u);
  return (u16)(u >> 16);
}
static __device__ __forceinline__ float bf2f(u16 h) {
  return __builtin_bit_cast(float, (unsigned)h << 16);
}

// async global->LDS, 16B per lane. LDS dest must be wave-uniform base
// (HW adds lane*16); global src is per-lane.
static __device__ __forceinline__ void gload16(u16* lds, const u16* g) {
  __builtin_amdgcn_global_load_lds(
      (__attribute__((address_space(1))) unsigned int*)(void*)(g),
      (__attribute__((address_space(3))) unsigned int*)(lds), 16, 0, 0);
}

// ---------------------------------------------------------------------------
// fp32 -> bf16 cast (weights)
// ---------------------------------------------------------------------------
__global__ __launch_bounds__(256) void cast_f32_bf16(
    const float* __restrict__ s, u16* __restrict__ d, int n4) {
  int i = blockIdx.x * 256 + threadIdx.x;
  if (i < n4) {
    float4 v = ((const float4*)s)[i];
    u16x4 o;
    o[0] = f2bf(v.x); o[1] = f2bf(v.y); o[2] = f2bf(v.z); o[3] = f2bf(v.w);
    ((u16x4*)d)[i] = o;
  }
}

// ---------------------------------------------------------------------------
// LayerNorm over D=1024. One block per row. Writes fp32 + bf16 copies.
// ---------------------------------------------------------------------------
__global__ __launch_bounds__(256) void ln_kernel(
    const float* __restrict__ in, const float* __restrict__ g,
    const float* __restrict__ bb, float* __restrict__ outf,
    u16* __restrict__ outb) {
  const int row = blockIdx.x;
  const int t = threadIdx.x;
  const float4 v = ((const float4*)(in + (size_t)row * 1024))[t];
  float s  = v.x + v.y + v.z + v.w;
  float sq = v.x * v.x + v.y * v.y + v.z * v.z + v.w * v.w;
#pragma unroll
  for (int off = 32; off > 0; off >>= 1) {
    s  += __shfl_down(s, off);
    sq += __shfl_down(sq, off);
  }
  __shared__ float red[8];
  const int w = t >> 6;
  if ((t & 63) == 0) { red[w] = s; red[4 + w] = sq; }
  __syncthreads();
  const float ts  = red[0] + red[1] + red[2] + red[3];
  const float tsq = red[4] + red[5] + red[6] + red[7];
  const float mu = ts * (1.0f / 1024.0f);
  const float rv = rsqrtf(tsq * (1.0f / 1024.0f) - mu * mu + 1e-5f);
  const float4 gv = ((const float4*)g)[t];
  const float4 bv = ((const float4*)bb)[t];
  float4 y;
  y.x = (v.x - mu) * rv * gv.x + bv.x;
  y.y = (v.y - mu) * rv * gv.y + bv.y;
  y.z = (v.z - mu) * rv * gv.z + bv.z;
  y.w = (v.w - mu) * rv * gv.w + bv.w;
  ((float4*)(outf + (size_t)row * 1024))[t] = y;
  u16x4 ob;
  ob[0] = f2bf(y.x); ob[1] = f2bf(y.y); ob[2] = f2bf(y.z); ob[3] = f2bf(y.w);
  *(u16x4*)(outb + (size_t)row * 1024 + t * 4) = ob;
}

// ---------------------------------------------------------------------------
// GEMM: C[m,n] = sum_k A[m,k]*W[n,k] + bias[n]   (A,W bf16; accum fp32)
// MODE 0: out bf16          MODE 1: GELU(exact) -> bf16
// MODE 2: out fp32 = res[m,n] + C[m,n]
// 128x128 tile, BK=32, 256 threads (4 waves 2x2), m97 structure.
// ---------------------------------------------------------------------------
#define BM 128
#define BN 128
#define BK 32

template <int MODE>
__global__ __launch_bounds__(256) void gemm_bt(
    const u16* __restrict__ A, const u16* __restrict__ W,
    const float* __restrict__ bias, const float* __restrict__ res,
    u16* __restrict__ outb, float* __restrict__ outf, int Nn, int K) {
  __shared__ u16 As[BM * BK];  // 8 KB, row-major [128][32]
  __shared__ u16 Bs[BN * BK];  // 8 KB
  const int t  = threadIdx.x;
  const int w  = t >> 6;
  const int ln = t & 63;
  const int lr = ln & 15;
  const int lg = ln >> 4;
  const int bm = blockIdx.x * BM;
  const int bn = blockIdx.y * BN;
  const int wm = (w >> 1) * 64;
  const int wn = (w & 1) * 64;

  f32x4 acc[4][4] = {};

  const int sr = t >> 2;          // staging row 0..63 (round 0), +64 round 1
  const int sk = (t & 3) * 8;     // staging k offset (elems)
  const u16* gA = A + (size_t)(bm + sr) * K + sk;
  const u16* gB = W + (size_t)(bn + sr) * K + sk;
  const int ldsOff = w * 512;     // u16 units; round 1 adds 2048

  const int kSteps = K >> 5;
  for (int kt = 0; kt < kSteps; ++kt) {
    __syncthreads();
    const u16* ga = gA + kt * BK;
    const u16* gb = gB + kt * BK;
    gload16(As + ldsOff,        ga);
    gload16(As + ldsOff + 2048, ga + (size_t)64 * K);
    gload16(Bs + ldsOff,        gb);
    gload16(Bs + ldsOff + 2048, gb + (size_t)64 * K);
    __syncthreads();

    bf16x8 af[4], bfr[4];
#pragma unroll
    for (int mi = 0; mi < 4; ++mi)
      af[mi] = *(const bf16x8*)(As + (wm + mi * 16 + lr) * BK + lg * 8);
#pragma unroll
    for (int ni = 0; ni < 4; ++ni)
      bfr[ni] = *(const bf16x8*)(Bs + (wn + ni * 16 + lr) * BK + lg * 8);
#pragma unroll
    for (int mi = 0; mi < 4; ++mi)
#pragma unroll
      for (int ni = 0; ni < 4; ++ni)
        acc[mi][ni] = __builtin_amdgcn_mfma_f32_16x16x32_bf16(
            af[mi], bfr[ni], acc[mi][ni], 0, 0, 0);
  }

  // epilogue: C/D layout col = lane&15, row = (lane>>4)*4 + reg
#pragma unroll
  for (int ni = 0; ni < 4; ++ni) {
    const int col = bn + wn + ni * 16 + lr;
    const float bv = bias[col];
#pragma unroll
    for (int mi = 0; mi < 4; ++mi) {
      const int row0 = bm + wm + mi * 16 + lg * 4;
#pragma unroll
      for (int r = 0; r < 4; ++r) {
        float v = acc[mi][ni][r] + bv;
        const size_t idx = (size_t)(row0 + r) * Nn + col;
        if (MODE == 1) v = 0.5f * v * (1.0f + erff(v * 0.70710678118654752f));
        if (MODE == 2) outf[idx] = res[idx] + v;
        else           outb[idx] = f2bf(v);
      }
    }
  }
}

// ---------------------------------------------------------------------------
// Flash attention. qkv bf16 [B*N, 3072] (q|k|v each 1024, head-major 16x64).
// Block: 64 q rows (4 waves x 16) for one (b,h); KBLK=64 keys/iter.
// LDS rows padded to 72 elems (144 B) -> bank-uniform b128 access.
// Q pre-scaled by 1/sqrt(64)=0.125 (exact in bf16).
// ---------------------------------------------------------------------------
__global__ __launch_bounds__(256) void attn_kernel(
    const u16* __restrict__ qkv, u16* __restrict__ o) {
  __shared__ u16 Ks[64 * 72];      // K tile  [key][d]
  __shared__ u16 Vs[64 * 72];      // V^T tile [d][key]
  __shared__ u16 Ps[4][16 * 72];   // per-wave P tile [q][key]
  const int t  = threadIdx.x;
  const int w  = t >> 6;
  const int ln = t & 63;
  const int lr = ln & 15;
  const int lg = ln >> 4;
  const int b  = blockIdx.y >> 4;
  const int h  = blockIdx.y & 15;
  const int qb = blockIdx.x * 64;
  const size_t baseRow = (size_t)b * 2048;

  // Q fragments (A-operand: row = lane&15, k contiguous 8 at (lane>>4)*8)
  bf16x8 qf[2];
  {
    const u16* qp = qkv + (baseRow + qb + w * 16 + lr) * 3072 + h * 64 + lg * 8;
#pragma unroll
    for (int kc = 0; kc < 2; ++kc) {
      u16x8 raw = *(const u16x8*)(qp + kc * 32);
#pragma unroll
      for (int i = 0; i < 8; ++i)
        qf[kc][i] = (short)f2bf(bf2f(raw[i]) * 0.125f);
    }
  }

  f32x4 oacc[4] = {};
  float mrun[4], lrun[4];
#pragma unroll
  for (int r = 0; r < 4; ++r) { mrun[r] = -3.0e38f; lrun[r] = 0.0f; }

  const int skk = t >> 3;          // staging key row 0..31 (+32 round 1)
  const int sd0 = (t & 7) * 8;     // staging d offset

  for (int kt = 0; kt < 32; ++kt) {
    __syncthreads();
#pragma unroll
    for (int r2 = 0; r2 < 2; ++r2) {
      const int kk = r2 * 32 + skk;
      const u16* kp = qkv + (baseRow + kt * 64 + kk) * 3072 + h * 64 + sd0;
      u16x8 kv = *(const u16x8*)(kp + 1024);
      *(u16x8*)(Ks + kk * 72 + sd0) = kv;
      u16x8 vv = *(const u16x8*)(kp + 2048);
#pragma unroll
      for (int j = 0; j < 8; ++j) Vs[(sd0 + j) * 72 + kk] = vv[j];
    }
    __syncthreads();

    // S = (Q*0.125) K^T : s[ni] holds S[q=lg*4+r][key=ni*16+lr]
    f32x4 s[4] = {};
#pragma unroll
    for (int kc = 0; kc < 2; ++kc)
#pragma unroll
      for (int ni = 0; ni < 4; ++ni) {
        bf16x8 kb = *(const bf16x8*)(Ks + (ni * 16 + lr) * 72 + kc * 32 + lg * 8);
        s[ni] = __builtin_amdgcn_mfma_f32_16x16x32_bf16(qf[kc], kb, s[ni], 0, 0, 0);
      }

    // online softmax (rows lg*4+r live on the 16 lanes sharing lg)
    float mx[4];
#pragma unroll
    for (int r = 0; r < 4; ++r)
      mx[r] = fmaxf(fmaxf(s[0][r], s[1][r]), fmaxf(s[2][r], s[3][r]));
#pragma unroll
    for (int off = 1; off <= 8; off <<= 1)
#pragma unroll
      for (int r = 0; r < 4; ++r)
        mx[r] = fmaxf(mx[r], __shfl_xor(mx[r], off));

    float al[4], ps[4];
#pragma unroll
    for (int r = 0; r < 4; ++r) {
      const float mn = fmaxf(mrun[r], mx[r]);
      al[r] = __expf(mrun[r] - mn);
      mrun[r] = mn;
      ps[r] = 0.0f;
    }
#pragma unroll
    for (int ni = 0; ni < 4; ++ni)
#pragma unroll
      for (int r = 0; r < 4; ++r) {
        const float p = __expf(s[ni][r] - mrun[r]);
        ps[r] += p;
        Ps[w][(lg * 4 + r) * 72 + ni * 16 + lr] = f2bf(p);
      }
#pragma unroll
    for (int off = 1; off <= 8; off <<= 1)
#pragma unroll
      for (int r = 0; r < 4; ++r)
        ps[r] += __shfl_xor(ps[r], off);
#pragma unroll
    for (int r = 0; r < 4; ++r) lrun[r] = lrun[r] * al[r] + ps[r];
#pragma unroll
    for (int di = 0; di < 4; ++di)
#pragma unroll
      for (int r = 0; r < 4; ++r) oacc[di][r] *= al[r];

    // O += P V : A = P (rows q), B = V^T rows d (contiguous k)
#pragma unroll
    for (int kc = 0; kc < 2; ++kc) {
      bf16x8 pa = *(const bf16x8*)(Ps[w] + lr * 72 + kc * 32 + lg * 8);
#pragma unroll
      for (int di = 0; di < 4; ++di) {
        bf16x8 vb = *(const bf16x8*)(Vs + (di * 16 + lr) * 72 + kc * 32 + lg * 8);
        oacc[di] = __builtin_amdgcn_mfma_f32_16x16x32_bf16(pa, vb, oacc[di], 0, 0, 0);
      }
    }
  }

#pragma unroll
  for (int r = 0; r < 4; ++r) {
    const float inv = 1.0f / lrun[r];
    const size_t orow = baseRow + qb + w * 16 + lg * 4 + r;
#pragma unroll
    for (int di = 0; di < 4; ++di)
      o[orow * 1024 + h * 64 + di * 16 + lr] = f2bf(oacc[di][r] * inv);
  }
}

// ---------------------------------------------------------------------------
// Launch: L=2 layers of  x=LN1(x); x+=MHA(x); x=LN2(x); x+=FC2(gelu(FC1(x)))
// ---------------------------------------------------------------------------
extern "C" void kernel_launch(void* const* d_in, const int* in_sizes, int n_in,
                              void* d_out, int out_size, void* d_ws,
                              size_t ws_size, hipStream_t stream) {
  const float* tokens = (const float*)d_in[0];
  const float* ln1_g  = (const float*)d_in[1];
  const float* ln1_b  = (const float*)d_in[2];
  const float* qkv_w  = (const float*)d_in[3];
  const float* qkv_b  = (const float*)d_in[4];
  const float* out_w  = (const float*)d_in[5];
  const float* out_b  = (const float*)d_in[6];
  const float* ln2_g  = (const float*)d_in[7];
  const float* ln2_b  = (const float*)d_in[8];
  const float* fc1_w  = (const float*)d_in[9];
  const float* fc1_b  = (const float*)d_in[10];
  const float* fc2_w  = (const float*)d_in[11];
  const float* fc2_b  = (const float*)d_in[12];
  float* xf = (float*)d_out;  // running activation, fp32 [8192,1024]

  char* ws = (char*)d_ws;
  size_t off = 0;
  auto take = [&](size_t bytes) {
    char* p = ws + off;
    off += (bytes + 255) & ~(size_t)255;
    return p;
  };
  u16* xn    = (u16*)take((size_t)8192 * 1024 * 2);   // normed x, bf16
  u16* big   = (u16*)take((size_t)8192 * 4096 * 2);   // qkv-out / fc1-out (disjoint lifetimes)
  u16* attnb = (u16*)take((size_t)8192 * 1024 * 2);   // attention out, bf16
  u16* qkvw  = (u16*)take((size_t)2 * 3072 * 1024 * 2);
  u16* outw  = (u16*)take((size_t)2 * 1024 * 1024 * 2);
  u16* fc1w  = (u16*)take((size_t)2 * 4096 * 1024 * 2);
  u16* fc2w  = (u16*)take((size_t)2 * 1024 * 4096 * 2);
  u16* qkvb16 = big;  // [8192, 3072]
  u16* hb     = big;  // [8192, 4096]

  cast_f32_bf16<<<6144, 256, 0, stream>>>(qkv_w, qkvw, 2 * 3072 * 1024 / 4);
  cast_f32_bf16<<<2048, 256, 0, stream>>>(out_w, outw, 2 * 1024 * 1024 / 4);
  cast_f32_bf16<<<8192, 256, 0, stream>>>(fc1_w, fc1w, 2 * 4096 * 1024 / 4);
  cast_f32_bf16<<<8192, 256, 0, stream>>>(fc2_w, fc2w, 2 * 1024 * 4096 / 4);

  for (int i = 0; i < 2; ++i) {
    ln_kernel<<<8192, 256, 0, stream>>>(i == 0 ? tokens : xf,
                                        ln1_g + i * 1024, ln1_b + i * 1024, xf, xn);
    gemm_bt<0><<<dim3(64, 24), 256, 0, stream>>>(
        xn, qkvw + (size_t)i * 3072 * 1024, qkv_b + i * 3072, nullptr,
        qkvb16, nullptr, 3072, 1024);
    attn_kernel<<<dim3(32, 64), 256, 0, stream>>>(qkvb16, attnb);
    gemm_bt<2><<<dim3(64, 8), 256, 0, stream>>>(
        attnb, outw + (size_t)i * 1024 * 1024, out_b + i * 1024, xf,
        nullptr, xf, 1024, 1024);
    ln_kernel<<<8192, 256, 0, stream>>>(xf, ln2_g + i * 1024, ln2_b + i * 1024,
                                        xf, xn);
    gemm_bt<1><<<dim3(64, 32), 256, 0, stream>>>(
        xn, fc1w + (size_t)i * 4096 * 1024, fc1_b + i * 4096, nullptr,
        hb, nullptr, 4096, 1024);
    gemm_bt<2><<<dim3(64, 8), 256, 0, stream>>>(
        hb, fc2w + (size_t)i * 1024 * 4096, fc2_b + i * 1024, xf,
        nullptr, xf, 1024, 4096);
  }
}